// Round 1
// baseline (405.511 us; speedup 1.0000x reference)
//
#include <hip/hip_runtime.h>
#include <hip/hip_bf16.h>

#define SEQ   2048
#define BATCH 2
#define NHEAD 16
#define HDIM  64
#define CDIM  1024
#define QKV_F 5120
#define SCALE 0.125f
#define EPSV  1e-5f

typedef __bf16 bf16;
typedef __bf16 bf16x8 __attribute__((ext_vector_type(8)));
typedef float  f32x4  __attribute__((ext_vector_type(4)));

#define MFMA16(a, b, c) __builtin_amdgcn_mfma_f32_16x16x32_bf16(a, b, c, 0, 0, 0)

// ---------------------------------------------------------------------------
// GEMM: C = A(MxK) * B(NnxK)^T, fp32 inputs converted to bf16 on stage.
// EPI 0: scatter to qkv_t[s][b][h][n][d] bf16, SCALE folded into q1/q2.
// EPI 1: fp32 out + bias (proj).
// ---------------------------------------------------------------------------
template <int EPI>
__global__ __launch_bounds__(256) void gemm_bt(
    const float* __restrict__ A, const float* __restrict__ Bw,
    const float* __restrict__ bias,
    bf16* __restrict__ outq, float* __restrict__ outp,
    int M, int Nn, int K)
{
    __shared__ __align__(16) bf16 As[128][72];
    __shared__ __align__(16) bf16 Bs[128][72];

    const int tid  = threadIdx.x;
    const int lane = tid & 63;
    const int wave = tid >> 6;
    const int wr = wave >> 1, wc = wave & 1;
    const int g = lane >> 4, fr = lane & 15;
    const int m0 = blockIdx.y * 128;
    const int n0 = blockIdx.x * 128;

    f32x4 acc[4][4];
#pragma unroll
    for (int m = 0; m < 4; ++m)
#pragma unroll
        for (int n = 0; n < 4; ++n) acc[m][n] = f32x4{0.f, 0.f, 0.f, 0.f};

    const int nkt = K >> 6;
    for (int kt = 0; kt < nkt; ++kt) {
        const int k0 = kt << 6;
        __syncthreads();
#pragma unroll
        for (int it = 0; it < 4; ++it) {
            int idx = it * 256 + tid;      // 0..1023 chunk of 8 elems
            int row = idx >> 3;
            int c8  = (idx & 7) << 3;
            {
                const float* gp = A + (size_t)(m0 + row) * K + k0 + c8;
                float4 u = *(const float4*)gp;
                float4 v = *(const float4*)(gp + 4);
                bf16x8 t;
                t[0] = (bf16)u.x; t[1] = (bf16)u.y; t[2] = (bf16)u.z; t[3] = (bf16)u.w;
                t[4] = (bf16)v.x; t[5] = (bf16)v.y; t[6] = (bf16)v.z; t[7] = (bf16)v.w;
                *(bf16x8*)(&As[row][c8]) = t;
            }
            {
                const float* gp = Bw + (size_t)(n0 + row) * K + k0 + c8;
                float4 u = *(const float4*)gp;
                float4 v = *(const float4*)(gp + 4);
                bf16x8 t;
                t[0] = (bf16)u.x; t[1] = (bf16)u.y; t[2] = (bf16)u.z; t[3] = (bf16)u.w;
                t[4] = (bf16)v.x; t[5] = (bf16)v.y; t[6] = (bf16)v.z; t[7] = (bf16)v.w;
                *(bf16x8*)(&Bs[row][c8]) = t;
            }
        }
        __syncthreads();
#pragma unroll
        for (int ks = 0; ks < 2; ++ks) {
            bf16x8 af[4], bfr[4];
#pragma unroll
            for (int m = 0; m < 4; ++m)
                af[m] = *(const bf16x8*)(&As[wr * 64 + m * 16 + fr][ks * 32 + g * 8]);
#pragma unroll
            for (int n = 0; n < 4; ++n)
                bfr[n] = *(const bf16x8*)(&Bs[wc * 64 + n * 16 + fr][ks * 32 + g * 8]);
#pragma unroll
            for (int m = 0; m < 4; ++m)
#pragma unroll
                for (int n = 0; n < 4; ++n)
                    acc[m][n] = MFMA16(af[m], bfr[n], acc[m][n]);
        }
    }

#pragma unroll
    for (int m = 0; m < 4; ++m) {
#pragma unroll
        for (int n = 0; n < 4; ++n) {
#pragma unroll
            for (int r = 0; r < 4; ++r) {
                int row = m0 + wr * 64 + m * 16 + g * 4 + r;
                int col = n0 + wc * 64 + n * 16 + fr;
                float v = acc[m][n][r];
                if (EPI == 0) {
                    int b = row >> 11, nn = row & (SEQ - 1);
                    int s = col >> 10, rem = col & (CDIM - 1);
                    int h = rem >> 6, d = rem & 63;
                    if (s < 2) v *= SCALE;   // fold softmax scale into q1,q2
                    outq[((size_t)((s * BATCH + b) * NHEAD + h) << 17) + (nn << 6) + d] = (bf16)v;
                } else {
                    outp[(size_t)row * Nn + col] = v + bias[col];
                }
            }
        }
    }
}

// ---------------------------------------------------------------------------
// Differential flash attention. Block: 4 waves x 16 Q-rows (QBLK=64).
// grid = (SEQ/64, BATCH*NHEAD)
// ---------------------------------------------------------------------------
__global__ __launch_bounds__(256) void diff_attn(
    const bf16* __restrict__ qkv,
    const float* __restrict__ lq1, const float* __restrict__ lk1,
    const float* __restrict__ lq2, const float* __restrict__ lk2,
    float* __restrict__ attn_out)
{
    __shared__ __align__(16) bf16 K1s[64][72];
    __shared__ __align__(16) bf16 K2s[64][72];
    __shared__ __align__(16) bf16 Vts[64][72];   // transposed: [d][kv]
    __shared__ __align__(16) bf16 Ps[4][16][72]; // per-wave P buffer

    const int tid = threadIdx.x;
    const int lane = tid & 63, wave = tid >> 6;
    const int g = lane >> 4, fr = lane & 15;
    const int bh = blockIdx.y;
    const int b = bh >> 4, h = bh & 15;
    const int q0 = blockIdx.x * 64 + wave * 16;

    float ls1 = 0.f, ls2 = 0.f;
    for (int i = 0; i < HDIM; ++i) { ls1 += lq1[i] * lk1[i]; ls2 += lq2[i] * lk2[i]; }
    const float lam = __expf(ls1) - __expf(ls2) + 0.8f;

    const size_t HS = (size_t)SEQ * HDIM;  // 131072
    const bf16* q1p = qkv + ((size_t)((0 * BATCH + b) * NHEAD + h)) * HS;
    const bf16* q2p = qkv + ((size_t)((1 * BATCH + b) * NHEAD + h)) * HS;
    const bf16* k1p = qkv + ((size_t)((2 * BATCH + b) * NHEAD + h)) * HS;
    const bf16* k2p = qkv + ((size_t)((3 * BATCH + b) * NHEAD + h)) * HS;
    const bf16* vp  = qkv + ((size_t)((4 * BATCH + b) * NHEAD + h)) * HS;

    bf16x8 q1f[2], q2f[2];
#pragma unroll
    for (int ks = 0; ks < 2; ++ks) {
        q1f[ks] = *(const bf16x8*)(q1p + (size_t)(q0 + fr) * 64 + ks * 32 + g * 8);
        q2f[ks] = *(const bf16x8*)(q2p + (size_t)(q0 + fr) * 64 + ks * 32 + g * 8);
    }

    f32x4 o1[4], o2[4];
    float m1[4], l1[4], m2[4], l2[4];
#pragma unroll
    for (int n = 0; n < 4; ++n) { o1[n] = f32x4{0, 0, 0, 0}; o2[n] = f32x4{0, 0, 0, 0}; }
#pragma unroll
    for (int r = 0; r < 4; ++r) { m1[r] = -1e30f; l1[r] = 0.f; m2[r] = -1e30f; l2[r] = 0.f; }

    bf16x8 vf[2][4];

    auto process = [&](const bf16x8* qf, const bf16 (*Ks)[72],
                       f32x4* o, float* mS, float* lS) {
        f32x4 sa[4];
#pragma unroll
        for (int n = 0; n < 4; ++n) sa[n] = f32x4{0, 0, 0, 0};
#pragma unroll
        for (int ks = 0; ks < 2; ++ks) {
#pragma unroll
            for (int n = 0; n < 4; ++n) {
                bf16x8 kf = *(const bf16x8*)(&Ks[n * 16 + fr][ks * 32 + g * 8]);
                sa[n] = MFMA16(qf[ks], kf, sa[n]);
            }
        }
#pragma unroll
        for (int r = 0; r < 4; ++r) {
            float rm = fmaxf(fmaxf(sa[0][r], sa[1][r]), fmaxf(sa[2][r], sa[3][r]));
            rm = fmaxf(rm, __shfl_xor(rm, 1));
            rm = fmaxf(rm, __shfl_xor(rm, 2));
            rm = fmaxf(rm, __shfl_xor(rm, 4));
            rm = fmaxf(rm, __shfl_xor(rm, 8));
            float mn = fmaxf(mS[r], rm);
            float alpha = __expf(mS[r] - mn);
            float pn[4], rs = 0.f;
#pragma unroll
            for (int n = 0; n < 4; ++n) {
                pn[n] = __expf(sa[n][r] - mn);
                rs += pn[n];
                Ps[wave][g * 4 + r][n * 16 + fr] = (bf16)pn[n];
            }
            rs += __shfl_xor(rs, 1);
            rs += __shfl_xor(rs, 2);
            rs += __shfl_xor(rs, 4);
            rs += __shfl_xor(rs, 8);
            lS[r] = lS[r] * alpha + rs;
            mS[r] = mn;
#pragma unroll
            for (int n = 0; n < 4; ++n) o[n][r] *= alpha;
        }
#pragma unroll
        for (int ks = 0; ks < 2; ++ks) {
            bf16x8 pa = *(const bf16x8*)(&Ps[wave][fr][ks * 32 + g * 8]);
#pragma unroll
            for (int n = 0; n < 4; ++n) o[n] = MFMA16(pa, vf[ks][n], o[n]);
        }
    };

    for (int kt = 0; kt < SEQ / 64; ++kt) {
        __syncthreads();
#pragma unroll
        for (int it = 0; it < 2; ++it) {
            int idx = it * 256 + tid;     // 0..511
            int kv = idx >> 3;
            int c8 = (idx & 7) << 3;
            *(bf16x8*)(&K1s[kv][c8]) = *(const bf16x8*)(k1p + (size_t)(kt * 64 + kv) * 64 + c8);
            *(bf16x8*)(&K2s[kv][c8]) = *(const bf16x8*)(k2p + (size_t)(kt * 64 + kv) * 64 + c8);
            bf16x8 vv = *(const bf16x8*)(vp + (size_t)(kt * 64 + kv) * 64 + c8);
#pragma unroll
            for (int j = 0; j < 8; ++j) Vts[c8 + j][kv] = vv[j];
        }
        __syncthreads();

#pragma unroll
        for (int ks = 0; ks < 2; ++ks)
#pragma unroll
            for (int n = 0; n < 4; ++n)
                vf[ks][n] = *(const bf16x8*)(&Vts[n * 16 + fr][ks * 32 + g * 8]);

        process(q1f, K1s, o1, m1, l1);
        process(q2f, K2s, o2, m2, l2);
    }

#pragma unroll
    for (int r = 0; r < 4; ++r) {
        float i1 = 1.f / l1[r];
        float i2 = lam / l2[r];
        int nq = q0 + g * 4 + r;
        float* op = attn_out + ((size_t)(b * SEQ + nq)) * CDIM + h * HDIM;
#pragma unroll
        for (int n = 0; n < 4; ++n)
            op[n * 16 + fr] = o1[n][r] * i1 - o2[n][r] * i2;
    }
}

// ---------------------------------------------------------------------------
// In-place RMSNorm over last dim (1024) + 0.2 scale. grid = 4096 rows.
// ---------------------------------------------------------------------------
__global__ __launch_bounds__(256) void rmsnorm_inplace(float* __restrict__ io)
{
    __shared__ float red[4];
    const int row = blockIdx.x, tid = threadIdx.x;
    float4* p = (float4*)(io + (size_t)row * CDIM);
    float4 v = p[tid];
    float ss = v.x * v.x + v.y * v.y + v.z * v.z + v.w * v.w;
#pragma unroll
    for (int m = 1; m < 64; m <<= 1) ss += __shfl_xor(ss, m);
    if ((tid & 63) == 0) red[tid >> 6] = ss;
    __syncthreads();
    float tot = red[0] + red[1] + red[2] + red[3];
    float sc = rsqrtf(tot * (1.f / CDIM) + EPSV) * 0.2f;
    v.x *= sc; v.y *= sc; v.z *= sc; v.w *= sc;
    p[tid] = v;
}

extern "C" void kernel_launch(void* const* d_in, const int* in_sizes, int n_in,
                              void* d_out, int out_size, void* d_ws, size_t ws_size,
                              hipStream_t stream)
{
    (void)in_sizes; (void)n_in; (void)out_size; (void)ws_size;
    const float* x      = (const float*)d_in[0];
    const float* qkv_w  = (const float*)d_in[1];
    const float* proj_w = (const float*)d_in[2];
    const float* proj_b = (const float*)d_in[3];
    const float* lq1    = (const float*)d_in[4];
    const float* lk1    = (const float*)d_in[5];
    const float* lq2    = (const float*)d_in[6];
    const float* lk2    = (const float*)d_in[7];
    float* out = (float*)d_out;

    bf16*  qkv_t    = (bf16*)d_ws;
    float* attn_out = (float*)((char*)d_ws +
                       (size_t)5 * BATCH * NHEAD * SEQ * HDIM * sizeof(bf16)); // +40MB

    dim3 blk(256);
    // 1) QKV projection -> bf16 qkv_t[s][b][h][n][d], SCALE folded into q1/q2
    gemm_bt<0><<<dim3(QKV_F / 128, (BATCH * SEQ) / 128), blk, 0, stream>>>(
        x, qkv_w, nullptr, qkv_t, nullptr, BATCH * SEQ, QKV_F, CDIM);
    // 2) dual flash attention -> fp32 (B,N,C)
    diff_attn<<<dim3(SEQ / 64, BATCH * NHEAD), blk, 0, stream>>>(
        qkv_t, lq1, lk1, lq2, lk2, attn_out);
    // 3) RMSNorm (in place) * 0.2
    rmsnorm_inplace<<<dim3(BATCH * SEQ), blk, 0, stream>>>(attn_out);
    // 4) output projection + bias -> d_out fp32
    gemm_bt<1><<<dim3(CDIM / 128, (BATCH * SEQ) / 128), blk, 0, stream>>>(
        attn_out, proj_w, proj_b, nullptr, out, BATCH * SEQ, CDIM, CDIM);
}

// Round 2
// 250.972 us; speedup vs baseline: 1.6158x; 1.6158x over previous
//
#include <hip/hip_runtime.h>
#include <hip/hip_bf16.h>

#define SEQ   2048
#define BATCH 2
#define NHEAD 16
#define HDIM  64
#define CDIM  1024
#define QKV_F 5120
#define SCALE 0.125f
#define EPSV  1e-5f

typedef __bf16 bf16;
typedef __bf16 bf16x8 __attribute__((ext_vector_type(8)));
typedef float  f32x4  __attribute__((ext_vector_type(4)));
typedef float  f32x16 __attribute__((ext_vector_type(16)));

#define MFMA16(a, b, c) __builtin_amdgcn_mfma_f32_16x16x32_bf16(a, b, c, 0, 0, 0)
#define MFMA32(a, b, c) __builtin_amdgcn_mfma_f32_32x32x16_bf16(a, b, c, 0, 0, 0)

__device__ __forceinline__ unsigned pkbf(float a, float b) {
    union { bf16 h[2]; unsigned u; } t;
    t.h[0] = (bf16)a; t.h[1] = (bf16)b;
    return t.u;
}
__device__ __forceinline__ unsigned short bfbits(float a) {
    union { bf16 h; unsigned short u; } t;
    t.h = (bf16)a;
    return t.u;
}

// ---------------------------------------------------------------------------
// GEMM: C = A(MxK) * B(NnxK)^T, fp32 inputs converted to bf16 on stage.
// EPI 0: scatter to qkv_t layout; q1/q2 pre-scaled; V written TRANSPOSED
//        ([b][h][d][n]) so attention can stage V^T without an LDS transpose.
// EPI 1: fp32 out + bias (proj).
// ---------------------------------------------------------------------------
template <int EPI>
__global__ __launch_bounds__(256) void gemm_bt(
    const float* __restrict__ A, const float* __restrict__ Bw,
    const float* __restrict__ bias,
    bf16* __restrict__ outq, float* __restrict__ outp,
    int M, int Nn, int K)
{
    __shared__ __align__(16) bf16 As[128][72];
    __shared__ __align__(16) bf16 Bs[128][72];

    const int tid  = threadIdx.x;
    const int lane = tid & 63;
    const int wave = tid >> 6;
    const int wr = wave >> 1, wc = wave & 1;
    const int g = lane >> 4, fr = lane & 15;
    const int m0 = blockIdx.y * 128;
    const int n0 = blockIdx.x * 128;

    f32x4 acc[4][4];
#pragma unroll
    for (int m = 0; m < 4; ++m)
#pragma unroll
        for (int n = 0; n < 4; ++n) acc[m][n] = f32x4{0.f, 0.f, 0.f, 0.f};

    const int nkt = K >> 6;
    for (int kt = 0; kt < nkt; ++kt) {
        const int k0 = kt << 6;
        __syncthreads();
#pragma unroll
        for (int it = 0; it < 4; ++it) {
            int idx = it * 256 + tid;
            int row = idx >> 3;
            int c8  = (idx & 7) << 3;
            {
                const float* gp = A + (size_t)(m0 + row) * K + k0 + c8;
                float4 u = *(const float4*)gp;
                float4 v = *(const float4*)(gp + 4);
                bf16x8 t;
                t[0] = (bf16)u.x; t[1] = (bf16)u.y; t[2] = (bf16)u.z; t[3] = (bf16)u.w;
                t[4] = (bf16)v.x; t[5] = (bf16)v.y; t[6] = (bf16)v.z; t[7] = (bf16)v.w;
                *(bf16x8*)(&As[row][c8]) = t;
            }
            {
                const float* gp = Bw + (size_t)(n0 + row) * K + k0 + c8;
                float4 u = *(const float4*)gp;
                float4 v = *(const float4*)(gp + 4);
                bf16x8 t;
                t[0] = (bf16)u.x; t[1] = (bf16)u.y; t[2] = (bf16)u.z; t[3] = (bf16)u.w;
                t[4] = (bf16)v.x; t[5] = (bf16)v.y; t[6] = (bf16)v.z; t[7] = (bf16)v.w;
                *(bf16x8*)(&Bs[row][c8]) = t;
            }
        }
        __syncthreads();
#pragma unroll
        for (int ks = 0; ks < 2; ++ks) {
            bf16x8 af[4], bfr[4];
#pragma unroll
            for (int m = 0; m < 4; ++m)
                af[m] = *(const bf16x8*)(&As[wr * 64 + m * 16 + fr][ks * 32 + g * 8]);
#pragma unroll
            for (int n = 0; n < 4; ++n)
                bfr[n] = *(const bf16x8*)(&Bs[wc * 64 + n * 16 + fr][ks * 32 + g * 8]);
#pragma unroll
            for (int m = 0; m < 4; ++m)
#pragma unroll
                for (int n = 0; n < 4; ++n)
                    acc[m][n] = MFMA16(af[m], bfr[n], acc[m][n]);
        }
    }

#pragma unroll
    for (int m = 0; m < 4; ++m) {
#pragma unroll
        for (int n = 0; n < 4; ++n) {
            const int row0 = m0 + wr * 64 + m * 16 + g * 4;
            const int col  = n0 + wc * 64 + n * 16 + fr;
            if (EPI == 0) {
                const int bb = row0 >> 11, nn = row0 & (SEQ - 1);
                const int sI = col >> 10, rem = col & (CDIM - 1);
                const int hh = rem >> 6, dd = rem & 63;
                const size_t base = ((size_t)((sI * BATCH + bb) * NHEAD + hh)) << 17;
                if (sI == 4) {
                    // V transposed: vt[d][n], 4 consecutive tokens -> 8B store
                    ushort4 u;
                    u.x = bfbits(acc[m][n][0]);
                    u.y = bfbits(acc[m][n][1]);
                    u.z = bfbits(acc[m][n][2]);
                    u.w = bfbits(acc[m][n][3]);
                    *(ushort4*)(outq + base + ((size_t)dd << 11) + nn) = u;
                } else {
                    const float sc = (sI < 2) ? SCALE : 1.f;
#pragma unroll
                    for (int r = 0; r < 4; ++r)
                        outq[base + ((size_t)(nn + r) << 6) + dd] = (bf16)(acc[m][n][r] * sc);
                }
            } else {
#pragma unroll
                for (int r = 0; r < 4; ++r)
                    outp[(size_t)(row0 + r) * Nn + col] = acc[m][n][r] + bias[col];
            }
        }
    }
}

// ---------------------------------------------------------------------------
// Differential flash attention, m214-style structure:
//   S^T = mfma32(K, Q)   -> lane owns one q column, softmax in-register
//   O^T = mfma32(V^T, P) -> same q-per-lane layout, rescale lane-local
// 8 waves x 32 q-rows; KV tile 64; K/V^T LDS with XOR-swizzle (G4).
// grid = (SEQ/256, BATCH*NHEAD), block = 512
// ---------------------------------------------------------------------------
__device__ __forceinline__ void attn_state(
    const char* __restrict__ Ks, const bf16x8* qf, const bf16x8 (*vf)[2],
    int lq, int hi, int s32,
    f32x16& oa, f32x16& ob, float& mS, float& lS)
{
    // QK^T (swapped): S^T[kv][q]
    f32x16 s;
#pragma unroll
    for (int r = 0; r < 16; ++r) s[r] = 0.f;
    const int krow = s32 * 32 + lq;
    const int ksw  = (krow & 7) << 4;
#pragma unroll
    for (int ks = 0; ks < 4; ++ks) {
        bf16x8 kf = *(const bf16x8*)(Ks + krow * 128 + ((ks * 32 + hi * 16) ^ ksw));
        s = MFMA32(kf, qf[ks], s);
    }
    // row max (per q = lane column)
    float pm = s[0];
#pragma unroll
    for (int r = 1; r < 16; ++r) pm = fmaxf(pm, s[r]);
    pm = fmaxf(pm, __shfl_xor(pm, 32));
    // defer-max: only rescale when max grew by > 8
    if (!__all(pm <= mS + 8.f)) {
        float mn = fmaxf(mS, pm);
        float alpha = __expf(mS - mn);
        lS *= alpha;
        oa *= alpha;
        ob *= alpha;
        mS = mn;
    }
    float p[16];
    float rs = 0.f;
#pragma unroll
    for (int r = 0; r < 16; ++r) { p[r] = __expf(s[r] - mS); rs += p[r]; }
    rs += __shfl_xor(rs, 32);
    lS += rs;
    // pack P -> bf16 B-fragments via permlane32_swap (T12)
#pragma unroll
    for (int s16 = 0; s16 < 2; ++s16) {
        unsigned X = pkbf(p[s16 * 8 + 0], p[s16 * 8 + 1]);
        unsigned Z = pkbf(p[s16 * 8 + 2], p[s16 * 8 + 3]);
        unsigned Y = pkbf(p[s16 * 8 + 4], p[s16 * 8 + 5]);
        unsigned W = pkbf(p[s16 * 8 + 6], p[s16 * 8 + 7]);
        auto xy = __builtin_amdgcn_permlane32_swap(X, Y, false, false);
        auto zw = __builtin_amdgcn_permlane32_swap(Z, W, false, false);
        union { unsigned u[4]; bf16x8 v; } pf;
        pf.u[0] = xy[0]; pf.u[1] = zw[0]; pf.u[2] = xy[1]; pf.u[3] = zw[1];
        oa = MFMA32(vf[0][s16], pf.v, oa);
        ob = MFMA32(vf[1][s16], pf.v, ob);
    }
}

__global__ __launch_bounds__(512, 2) void diff_attn(
    const bf16* __restrict__ qkv,
    const float* __restrict__ lq1, const float* __restrict__ lk1,
    const float* __restrict__ lq2, const float* __restrict__ lk2,
    float* __restrict__ attn_out)
{
    __shared__ __align__(16) char K1s[64 * 128];
    __shared__ __align__(16) char K2s[64 * 128];
    __shared__ __align__(16) char Vts[64 * 128];

    const int tid = threadIdx.x;
    const int lane = tid & 63, wave = tid >> 6;
    const int lq = lane & 31, hi = lane >> 5;
    const int bh = blockIdx.y, b = bh >> 4, h = bh & 15;
    const int q0w = blockIdx.x * 256 + wave * 32;

    float ls1 = 0.f, ls2 = 0.f;
    for (int i = 0; i < HDIM; ++i) { ls1 += lq1[i] * lk1[i]; ls2 += lq2[i] * lk2[i]; }
    const float lam = __expf(ls1) - __expf(ls2) + 0.8f;

    const size_t HS = (size_t)SEQ * HDIM;
    const char* q1p = (const char*)(qkv + ((size_t)((0 * BATCH + b) * NHEAD + h)) * HS);
    const char* q2p = (const char*)(qkv + ((size_t)((1 * BATCH + b) * NHEAD + h)) * HS);
    const char* k1p = (const char*)(qkv + ((size_t)((2 * BATCH + b) * NHEAD + h)) * HS);
    const char* k2p = (const char*)(qkv + ((size_t)((3 * BATCH + b) * NHEAD + h)) * HS);
    const char* vtp = (const char*)(qkv + ((size_t)((4 * BATCH + b) * NHEAD + h)) * HS);

    // Q fragments (B-operand): lane holds Q[q0w+lq][ks*16 + hi*8 + j]
    bf16x8 qf1[4], qf2[4];
#pragma unroll
    for (int ks = 0; ks < 4; ++ks) {
        qf1[ks] = *(const bf16x8*)(q1p + (size_t)(q0w + lq) * 128 + ks * 32 + hi * 16);
        qf2[ks] = *(const bf16x8*)(q2p + (size_t)(q0w + lq) * 128 + ks * 32 + hi * 16);
    }

    f32x16 o1a, o1b, o2a, o2b;
#pragma unroll
    for (int r = 0; r < 16; ++r) { o1a[r] = 0.f; o1b[r] = 0.f; o2a[r] = 0.f; o2b[r] = 0.f; }
    float m1 = -1e30f, l1 = 0.f, m2 = -1e30f, l2 = 0.f;

    const int srow = tid >> 3;          // 0..63
    const int sc   = (tid & 7) << 4;    // byte col, 16B chunks
    const int swc  = sc ^ ((srow & 7) << 4);

    for (int kt = 0; kt < SEQ / 64; ++kt) {
        __syncthreads();
        uint4 ka = *(const uint4*)(k1p + (size_t)(kt * 64 + srow) * 128 + sc);
        uint4 kb = *(const uint4*)(k2p + (size_t)(kt * 64 + srow) * 128 + sc);
        uint4 vv = *(const uint4*)(vtp + (size_t)srow * (SEQ * 2) + kt * 128 + sc);
        *(uint4*)(K1s + srow * 128 + swc) = ka;
        *(uint4*)(K2s + srow * 128 + swc) = kb;
        *(uint4*)(Vts + srow * 128 + swc) = vv;
        __syncthreads();

#pragma unroll
        for (int s32 = 0; s32 < 2; ++s32) {
            // V^T fragments (A-operand): lane holds Vt[dt*32+lq][kv-slice]
            bf16x8 vf[2][2];
#pragma unroll
            for (int dt = 0; dt < 2; ++dt) {
                const int vrow = dt * 32 + lq;
                const int vsw  = (vrow & 7) << 4;
#pragma unroll
                for (int s16 = 0; s16 < 2; ++s16)
                    vf[dt][s16] = *(const bf16x8*)(Vts + vrow * 128 +
                                   ((s32 * 64 + s16 * 32 + hi * 16) ^ vsw));
            }
            attn_state(K1s, qf1, vf, lq, hi, s32, o1a, o1b, m1, l1);
            attn_state(K2s, qf2, vf, lq, hi, s32, o2a, o2b, m2, l2);
        }
    }

    const float i1 = 1.f / l1;
    const float i2 = lam / l2;
    const int nq = q0w + lq;
    float* op = attn_out + ((size_t)(b * SEQ + nq)) * CDIM + h * HDIM;
#pragma unroll
    for (int dt = 0; dt < 2; ++dt) {
        const f32x16& a1 = dt ? o1b : o1a;
        const f32x16& a2 = dt ? o2b : o2a;
#pragma unroll
        for (int rq = 0; rq < 4; ++rq) {
            const int d0 = dt * 32 + rq * 8 + hi * 4;
            float4 o;
            o.x = a1[rq * 4 + 0] * i1 - i2 * a2[rq * 4 + 0];
            o.y = a1[rq * 4 + 1] * i1 - i2 * a2[rq * 4 + 1];
            o.z = a1[rq * 4 + 2] * i1 - i2 * a2[rq * 4 + 2];
            o.w = a1[rq * 4 + 3] * i1 - i2 * a2[rq * 4 + 3];
            *(float4*)(op + d0) = o;
        }
    }
}

// ---------------------------------------------------------------------------
// In-place RMSNorm over last dim (1024) + 0.2 scale. grid = 4096 rows.
// ---------------------------------------------------------------------------
__global__ __launch_bounds__(256) void rmsnorm_inplace(float* __restrict__ io)
{
    __shared__ float red[4];
    const int row = blockIdx.x, tid = threadIdx.x;
    float4* p = (float4*)(io + (size_t)row * CDIM);
    float4 v = p[tid];
    float ss = v.x * v.x + v.y * v.y + v.z * v.z + v.w * v.w;
#pragma unroll
    for (int m = 1; m < 64; m <<= 1) ss += __shfl_xor(ss, m);
    if ((tid & 63) == 0) red[tid >> 6] = ss;
    __syncthreads();
    float tot = red[0] + red[1] + red[2] + red[3];
    float sc = rsqrtf(tot * (1.f / CDIM) + EPSV) * 0.2f;
    v.x *= sc; v.y *= sc; v.z *= sc; v.w *= sc;
    p[tid] = v;
}

extern "C" void kernel_launch(void* const* d_in, const int* in_sizes, int n_in,
                              void* d_out, int out_size, void* d_ws, size_t ws_size,
                              hipStream_t stream)
{
    (void)in_sizes; (void)n_in; (void)out_size; (void)ws_size;
    const float* x      = (const float*)d_in[0];
    const float* qkv_w  = (const float*)d_in[1];
    const float* proj_w = (const float*)d_in[2];
    const float* proj_b = (const float*)d_in[3];
    const float* lq1    = (const float*)d_in[4];
    const float* lk1    = (const float*)d_in[5];
    const float* lq2    = (const float*)d_in[6];
    const float* lk2    = (const float*)d_in[7];
    float* out = (float*)d_out;

    bf16*  qkv_t    = (bf16*)d_ws;
    float* attn_out = (float*)((char*)d_ws +
                       (size_t)5 * BATCH * NHEAD * SEQ * HDIM * sizeof(bf16)); // +40MB

    dim3 blk(256);
    gemm_bt<0><<<dim3(QKV_F / 128, (BATCH * SEQ) / 128), blk, 0, stream>>>(
        x, qkv_w, nullptr, qkv_t, nullptr, BATCH * SEQ, QKV_F, CDIM);
    diff_attn<<<dim3(SEQ / 256, BATCH * NHEAD), dim3(512), 0, stream>>>(
        qkv_t, lq1, lk1, lq2, lk2, attn_out);
    rmsnorm_inplace<<<dim3(BATCH * SEQ), blk, 0, stream>>>(attn_out);
    gemm_bt<1><<<dim3(CDIM / 128, (BATCH * SEQ) / 128), blk, 0, stream>>>(
        attn_out, proj_w, proj_b, nullptr, out, BATCH * SEQ, CDIM, CDIM);
}

// Round 3
// 226.450 us; speedup vs baseline: 1.7907x; 1.1083x over previous
//
#include <hip/hip_runtime.h>
#include <hip/hip_bf16.h>

#define SEQ   2048
#define BATCH 2
#define NHEAD 16
#define HDIM  64
#define CDIM  1024
#define QKV_F 5120
#define SCALE 0.125f
#define LOG2E 1.44269504f
#define EPSV  1e-5f

typedef __bf16 bf16;
typedef __bf16 bf16x4 __attribute__((ext_vector_type(4)));
typedef __bf16 bf16x8 __attribute__((ext_vector_type(8)));
typedef float  f32x4  __attribute__((ext_vector_type(4)));
typedef float  f32x16 __attribute__((ext_vector_type(16)));

#define MFMA16(a, b, c) __builtin_amdgcn_mfma_f32_16x16x32_bf16(a, b, c, 0, 0, 0)
#define MFMA32(a, b, c) __builtin_amdgcn_mfma_f32_32x32x16_bf16(a, b, c, 0, 0, 0)

__device__ __forceinline__ unsigned pkbf(float a, float b) {
    union { bf16 h[2]; unsigned u; } t;
    t.h[0] = (bf16)a; t.h[1] = (bf16)b;
    return t.u;
}
__device__ __forceinline__ unsigned short bfbits(float a) {
    union { bf16 h; unsigned short u; } t;
    t.h = (bf16)a;
    return t.u;
}
__device__ __forceinline__ void gload16(const void* g, void* l) {
    __builtin_amdgcn_global_load_lds(
        (const __attribute__((address_space(1))) unsigned int*)g,
        (__attribute__((address_space(3))) unsigned int*)l, 16, 0, 0);
}

// ---------------------------------------------------------------------------
// f32 -> bf16 convert, 8 elems/thread. grid = n/2048 (n % 2048 == 0).
// ---------------------------------------------------------------------------
__global__ __launch_bounds__(256) void cvt_bf16(
    const float* __restrict__ s, bf16* __restrict__ d)
{
    const int i = (blockIdx.x * 256 + threadIdx.x) * 8;
    float4 a = *(const float4*)(s + i);
    float4 b = *(const float4*)(s + i + 4);
    bf16x8 t;
    t[0] = (bf16)a.x; t[1] = (bf16)a.y; t[2] = (bf16)a.z; t[3] = (bf16)a.w;
    t[4] = (bf16)b.x; t[5] = (bf16)b.y; t[6] = (bf16)b.z; t[7] = (bf16)b.w;
    *(bf16x8*)(d + i) = t;
}

// ---------------------------------------------------------------------------
// m97-structure GEMM: C = A(MxK) * B(NnxK)^T, bf16 in, global_load_lds x16.
// 128x128 tile, BK=64, 4 waves. Linear LDS [128][64].
// EPI 0: scatter qkv (q1/q2 scaled by SCALE*LOG2E, V transposed [d][n]).
// EPI 1: fp32 + bias.
// ---------------------------------------------------------------------------
template <int EPI>
__global__ __launch_bounds__(256) void gemm_lds(
    const bf16* __restrict__ A, const bf16* __restrict__ Bw,
    const float* __restrict__ bias,
    bf16* __restrict__ outq, float* __restrict__ outp,
    int M, int Nn, int K)
{
    __shared__ __align__(16) bf16 As[128 * 64];
    __shared__ __align__(16) bf16 Bs[128 * 64];

    const int tid  = threadIdx.x;
    const int lane = tid & 63;
    const int wave = tid >> 6;
    const int wr = wave >> 1, wc = wave & 1;
    const int g = lane >> 4, fr = lane & 15;
    const int m0 = blockIdx.y * 128;
    const int n0 = blockIdx.x * 128;

    // staging geometry: chunk = wave*4+i covers LDS bytes [chunk*1024, +1024)
    const int lrow = lane >> 3;          // +row within 8-row chunk
    const int lcol = (lane & 7) << 3;    // element col (8 bf16 = 16B)

    f32x4 acc[4][4];
#pragma unroll
    for (int m = 0; m < 4; ++m)
#pragma unroll
        for (int n = 0; n < 4; ++n) acc[m][n] = f32x4{0.f, 0.f, 0.f, 0.f};

    const int nkt = K >> 6;
    for (int kt = 0; kt < nkt; ++kt) {
        const int k0 = kt << 6;
        __syncthreads();
#pragma unroll
        for (int i = 0; i < 4; ++i) {
            const int chunk = wave * 4 + i;
            const int row = chunk * 8 + lrow;
            gload16(A + (size_t)(m0 + row) * K + k0 + lcol, As + chunk * 512);
            gload16(Bw + (size_t)(n0 + row) * K + k0 + lcol, Bs + chunk * 512);
        }
        __syncthreads();
#pragma unroll
        for (int ks = 0; ks < 2; ++ks) {
            bf16x8 af[4], bfr[4];
#pragma unroll
            for (int m = 0; m < 4; ++m)
                af[m] = *(const bf16x8*)(As + (wr * 64 + m * 16 + fr) * 64 + ks * 32 + g * 8);
#pragma unroll
            for (int n = 0; n < 4; ++n)
                bfr[n] = *(const bf16x8*)(Bs + (wc * 64 + n * 16 + fr) * 64 + ks * 32 + g * 8);
#pragma unroll
            for (int m = 0; m < 4; ++m)
#pragma unroll
                for (int n = 0; n < 4; ++n)
                    acc[m][n] = MFMA16(af[m], bfr[n], acc[m][n]);
        }
    }

#pragma unroll
    for (int m = 0; m < 4; ++m) {
#pragma unroll
        for (int n = 0; n < 4; ++n) {
            const int row0 = m0 + wr * 64 + m * 16 + g * 4;
            const int col  = n0 + wc * 64 + n * 16 + fr;
            if (EPI == 0) {
                const int bb = row0 >> 11, nn = row0 & (SEQ - 1);
                const int sI = col >> 10, rem = col & (CDIM - 1);
                const int hh = rem >> 6, dd = rem & 63;
                const size_t base = ((size_t)((sI * BATCH + bb) * NHEAD + hh)) << 17;
                if (sI == 4) {
                    ushort4 u;
                    u.x = bfbits(acc[m][n][0]);
                    u.y = bfbits(acc[m][n][1]);
                    u.z = bfbits(acc[m][n][2]);
                    u.w = bfbits(acc[m][n][3]);
                    *(ushort4*)(outq + base + ((size_t)dd << 11) + nn) = u;
                } else {
                    const float sc = (sI < 2) ? SCALE * LOG2E : 1.f;
#pragma unroll
                    for (int r = 0; r < 4; ++r)
                        outq[base + ((size_t)(nn + r) << 6) + dd] = (bf16)(acc[m][n][r] * sc);
                }
            } else {
#pragma unroll
                for (int r = 0; r < 4; ++r)
                    outp[(size_t)(row0 + r) * Nn + col] = acc[m][n][r] + bias[col];
            }
        }
    }
}

// ---------------------------------------------------------------------------
// Differential flash attention (S^T = mfma32(K,Q), O^T = mfma32(V^T,P)).
// Q pre-scaled by SCALE*LOG2E so P = v_exp(S - m) directly (exp2 domain).
// ---------------------------------------------------------------------------
__device__ __forceinline__ void attn_state(
    const char* __restrict__ Ks, const bf16x8* qf, const bf16x8 (*vf)[2],
    int lq, int hi, int s32,
    f32x16& oa, f32x16& ob, float& mS, float& lS)
{
    f32x16 s;
#pragma unroll
    for (int r = 0; r < 16; ++r) s[r] = 0.f;
    const int krow = s32 * 32 + lq;
    const int ksw  = (krow & 7) << 4;
#pragma unroll
    for (int ks = 0; ks < 4; ++ks) {
        bf16x8 kf = *(const bf16x8*)(Ks + krow * 128 + ((ks * 32 + hi * 16) ^ ksw));
        s = MFMA32(kf, qf[ks], s);
    }
    float pm = s[0];
#pragma unroll
    for (int r = 1; r < 16; ++r) pm = fmaxf(pm, s[r]);
    pm = fmaxf(pm, __shfl_xor(pm, 32));
    // defer-max (threshold 8 in ln-domain = 11.54 in log2-domain)
    if (!__all(pm <= mS + 8.f * LOG2E)) {
        float mn = fmaxf(mS, pm);
        float alpha = __builtin_amdgcn_exp2f(mS - mn);
        lS *= alpha;
        oa *= alpha;
        ob *= alpha;
        mS = mn;
    }
    float p[16];
    float rs = 0.f;
#pragma unroll
    for (int r = 0; r < 16; ++r) { p[r] = __builtin_amdgcn_exp2f(s[r] - mS); rs += p[r]; }
    rs += __shfl_xor(rs, 32);
    lS += rs;
#pragma unroll
    for (int s16 = 0; s16 < 2; ++s16) {
        unsigned X = pkbf(p[s16 * 8 + 0], p[s16 * 8 + 1]);
        unsigned Z = pkbf(p[s16 * 8 + 2], p[s16 * 8 + 3]);
        unsigned Y = pkbf(p[s16 * 8 + 4], p[s16 * 8 + 5]);
        unsigned W = pkbf(p[s16 * 8 + 6], p[s16 * 8 + 7]);
        auto xy = __builtin_amdgcn_permlane32_swap(X, Y, false, false);
        auto zw = __builtin_amdgcn_permlane32_swap(Z, W, false, false);
        union { unsigned u[4]; bf16x8 v; } pf;
        pf.u[0] = xy[0]; pf.u[1] = zw[0]; pf.u[2] = xy[1]; pf.u[3] = zw[1];
        oa = MFMA32(vf[0][s16], pf.v, oa);
        ob = MFMA32(vf[1][s16], pf.v, ob);
    }
}

__global__ __launch_bounds__(512, 2) void diff_attn(
    const bf16* __restrict__ qkv,
    const float* __restrict__ lq1, const float* __restrict__ lk1,
    const float* __restrict__ lq2, const float* __restrict__ lk2,
    float* __restrict__ attn_out)
{
    __shared__ __align__(16) char K1s[64 * 128];
    __shared__ __align__(16) char K2s[64 * 128];
    __shared__ __align__(16) char Vts[64 * 128];

    const int tid = threadIdx.x;
    const int lane = tid & 63, wave = tid >> 6;
    const int lq = lane & 31, hi = lane >> 5;
    const int bh = blockIdx.y, b = bh >> 4, h = bh & 15;
    const int q0w = blockIdx.x * 256 + wave * 32;

    float ls1 = 0.f, ls2 = 0.f;
    for (int i = 0; i < HDIM; ++i) { ls1 += lq1[i] * lk1[i]; ls2 += lq2[i] * lk2[i]; }
    const float lam = __expf(ls1) - __expf(ls2) + 0.8f;

    const size_t HS = (size_t)SEQ * HDIM;
    const char* q1p = (const char*)(qkv + ((size_t)((0 * BATCH + b) * NHEAD + h)) * HS);
    const char* q2p = (const char*)(qkv + ((size_t)((1 * BATCH + b) * NHEAD + h)) * HS);
    const char* k1p = (const char*)(qkv + ((size_t)((2 * BATCH + b) * NHEAD + h)) * HS);
    const char* k2p = (const char*)(qkv + ((size_t)((3 * BATCH + b) * NHEAD + h)) * HS);
    const char* vtp = (const char*)(qkv + ((size_t)((4 * BATCH + b) * NHEAD + h)) * HS);

    bf16x8 qf1[4], qf2[4];
#pragma unroll
    for (int ks = 0; ks < 4; ++ks) {
        qf1[ks] = *(const bf16x8*)(q1p + (size_t)(q0w + lq) * 128 + ks * 32 + hi * 16);
        qf2[ks] = *(const bf16x8*)(q2p + (size_t)(q0w + lq) * 128 + ks * 32 + hi * 16);
    }

    f32x16 o1a, o1b, o2a, o2b;
#pragma unroll
    for (int r = 0; r < 16; ++r) { o1a[r] = 0.f; o1b[r] = 0.f; o2a[r] = 0.f; o2b[r] = 0.f; }
    float m1 = -1e30f, l1 = 0.f, m2 = -1e30f, l2 = 0.f;

    const int srow = tid >> 3;
    const int sc   = (tid & 7) << 4;
    const int swc  = sc ^ ((srow & 7) << 4);

    for (int kt = 0; kt < SEQ / 64; ++kt) {
        __syncthreads();
        uint4 ka = *(const uint4*)(k1p + (size_t)(kt * 64 + srow) * 128 + sc);
        uint4 kb = *(const uint4*)(k2p + (size_t)(kt * 64 + srow) * 128 + sc);
        uint4 vv = *(const uint4*)(vtp + (size_t)srow * (SEQ * 2) + kt * 128 + sc);
        *(uint4*)(K1s + srow * 128 + swc) = ka;
        *(uint4*)(K2s + srow * 128 + swc) = kb;
        *(uint4*)(Vts + srow * 128 + swc) = vv;
        __syncthreads();

#pragma unroll
        for (int s32 = 0; s32 < 2; ++s32) {
            bf16x8 vf[2][2];
#pragma unroll
            for (int dt = 0; dt < 2; ++dt) {
                const int vrow = dt * 32 + lq;
                const int vsw  = (vrow & 7) << 4;
#pragma unroll
                for (int s16 = 0; s16 < 2; ++s16)
                    vf[dt][s16] = *(const bf16x8*)(Vts + vrow * 128 +
                                   ((s32 * 64 + s16 * 32 + hi * 16) ^ vsw));
            }
            attn_state(K1s, qf1, vf, lq, hi, s32, o1a, o1b, m1, l1);
            attn_state(K2s, qf2, vf, lq, hi, s32, o2a, o2b, m2, l2);
        }
    }

    const float i1 = 1.f / l1;
    const float i2 = lam / l2;
    const int nq = q0w + lq;
    float* op = attn_out + ((size_t)(b * SEQ + nq)) * CDIM + h * HDIM;
#pragma unroll
    for (int dt = 0; dt < 2; ++dt) {
        const f32x16& a1 = dt ? o1b : o1a;
        const f32x16& a2 = dt ? o2b : o2a;
#pragma unroll
        for (int rq = 0; rq < 4; ++rq) {
            const int d0 = dt * 32 + rq * 8 + hi * 4;
            float4 o;
            o.x = a1[rq * 4 + 0] * i1 - i2 * a2[rq * 4 + 0];
            o.y = a1[rq * 4 + 1] * i1 - i2 * a2[rq * 4 + 1];
            o.z = a1[rq * 4 + 2] * i1 - i2 * a2[rq * 4 + 2];
            o.w = a1[rq * 4 + 3] * i1 - i2 * a2[rq * 4 + 3];
            *(float4*)(op + d0) = o;
        }
    }
}

// ---------------------------------------------------------------------------
// RMSNorm over last dim (1024) + 0.2 scale, fp32 in -> bf16 out.
// ---------------------------------------------------------------------------
__global__ __launch_bounds__(256) void rmsnorm_bf16(
    const float* __restrict__ in, bf16* __restrict__ out)
{
    __shared__ float red[4];
    const int row = blockIdx.x, tid = threadIdx.x;
    const float4 v = ((const float4*)(in + (size_t)row * CDIM))[tid];
    float ss = v.x * v.x + v.y * v.y + v.z * v.z + v.w * v.w;
#pragma unroll
    for (int m = 1; m < 64; m <<= 1) ss += __shfl_xor(ss, m);
    if ((tid & 63) == 0) red[tid >> 6] = ss;
    __syncthreads();
    float tot = red[0] + red[1] + red[2] + red[3];
    float sc = rsqrtf(tot * (1.f / CDIM) + EPSV) * 0.2f;
    bf16x4 o;
    o[0] = (bf16)(v.x * sc); o[1] = (bf16)(v.y * sc);
    o[2] = (bf16)(v.z * sc); o[3] = (bf16)(v.w * sc);
    ((bf16x4*)(out + (size_t)row * CDIM))[tid] = o;
}

extern "C" void kernel_launch(void* const* d_in, const int* in_sizes, int n_in,
                              void* d_out, int out_size, void* d_ws, size_t ws_size,
                              hipStream_t stream)
{
    (void)in_sizes; (void)n_in; (void)out_size; (void)ws_size;
    const float* x      = (const float*)d_in[0];
    const float* qkv_w  = (const float*)d_in[1];
    const float* proj_w = (const float*)d_in[2];
    const float* proj_b = (const float*)d_in[3];
    const float* lq1    = (const float*)d_in[4];
    const float* lk1    = (const float*)d_in[5];
    const float* lq2    = (const float*)d_in[6];
    const float* lk2    = (const float*)d_in[7];
    float* out = (float*)d_out;

    // workspace layout (68 MB):
    //   [0,40M)   qkv_t bf16   (later aliased: [0,8M) attn_b bf16)
    //   [40M,56M) attn_out f32 (earlier aliased: [40M,48M) x_bf16)
    //   [56M,66M) qkv_w bf16
    //   [66M,68M) proj_w bf16
    char* ws = (char*)d_ws;
    bf16*  qkv_t    = (bf16*)ws;
    bf16*  attn_b   = (bf16*)ws;
    float* attn_out = (float*)(ws + (size_t)40 * 1024 * 1024);
    bf16*  x_b      = (bf16*)(ws + (size_t)40 * 1024 * 1024);
    bf16*  qkvw_b   = (bf16*)(ws + (size_t)56 * 1024 * 1024);
    bf16*  projw_b  = (bf16*)(ws + (size_t)66 * 1024 * 1024);

    dim3 blk(256);
    // 0) converts (x aliases attn_out region — dead until diff_attn writes it)
    cvt_bf16<<<dim3((BATCH * SEQ * CDIM) / 2048), blk, 0, stream>>>(x, x_b);
    cvt_bf16<<<dim3((QKV_F * CDIM) / 2048), blk, 0, stream>>>(qkv_w, qkvw_b);
    cvt_bf16<<<dim3((CDIM * CDIM) / 2048), blk, 0, stream>>>(proj_w, projw_b);
    // 1) QKV projection
    gemm_lds<0><<<dim3(QKV_F / 128, (BATCH * SEQ) / 128), blk, 0, stream>>>(
        x_b, qkvw_b, nullptr, qkv_t, nullptr, BATCH * SEQ, QKV_F, CDIM);
    // 2) dual flash attention
    diff_attn<<<dim3(SEQ / 256, BATCH * NHEAD), dim3(512), 0, stream>>>(
        qkv_t, lq1, lk1, lq2, lk2, attn_out);
    // 3) RMSNorm -> bf16 (aliases qkv_t region — qkv_t dead after attn)
    rmsnorm_bf16<<<dim3(BATCH * SEQ), blk, 0, stream>>>(attn_out, attn_b);
    // 4) output projection + bias
    gemm_lds<1><<<dim3(CDIM / 128, (BATCH * SEQ) / 128), blk, 0, stream>>>(
        attn_b, projw_b, proj_b, nullptr, out, BATCH * SEQ, CDIM, CDIM);
}